// Round 7
// baseline (517.357 us; speedup 1.0000x reference)
//
#include <hip/hip_runtime.h>
#include <hip/hip_bf16.h>

typedef __attribute__((ext_vector_type(8))) short bf16x8;
typedef __attribute__((ext_vector_type(4))) float f32x4;

#define NB   256
#define TT   512
#define DDEC 512
#define DENC 1024
#define DATT 128
#define NF   32
#define KW   31
#define PW   15

__device__ __forceinline__ float fast_tanh(float x) {
  float e = __expf(2.f * x);
  return 1.f - 2.f / (e + 1.f);
}

// ---------- prep: WkT[a][k] = bf16(Wk[k][a]) ----------
__global__ __launch_bounds__(256) void prep_wkt(const float* __restrict__ Wk,
                                                __hip_bfloat16* __restrict__ WkT) {
  int idx = blockIdx.x * 256 + threadIdx.x;
  int k2 = idx >> 7, a = idx & 127;
  int k = k2 * 2;
  union { ushort2 u; __hip_bfloat16 h[2]; } cv;
  cv.h[0] = __float2bfloat16(Wk[(size_t)k * DATT + a]);
  cv.h[1] = __float2bfloat16(Wk[(size_t)(k + 1) * DATT + a]);
  *reinterpret_cast<ushort2*>(WkT + (size_t)a * 1024 + k) = cv.u;
}

// ---------- prep: qv[b][a] = query[b,:] @ Wq[:,a] ----------
__global__ __launch_bounds__(128) void prep_qv(const float* __restrict__ query,
                                               const float* __restrict__ Wq,
                                               float* __restrict__ qvg) {
  __shared__ float qr[DDEC];
  const int b = blockIdx.x, tid = threadIdx.x;
  for (int i = tid; i < DDEC; i += 128) qr[i] = query[(size_t)b * DDEC + i];
  __syncthreads();
  float a0 = 0.f, a1 = 0.f, a2 = 0.f, a3 = 0.f;
#pragma unroll 4
  for (int d = 0; d < DDEC; d += 4) {
    a0 = fmaf(qr[d + 0], Wq[(size_t)(d + 0) * DATT + tid], a0);
    a1 = fmaf(qr[d + 1], Wq[(size_t)(d + 1) * DATT + tid], a1);
    a2 = fmaf(qr[d + 2], Wq[(size_t)(d + 2) * DATT + tid], a2);
    a3 = fmaf(qr[d + 3], Wq[(size_t)(d + 3) * DATT + tid], a3);
  }
  qvg[(size_t)b * DATT + tid] = (a0 + a1) + (a2 + a3);
}

// ---------- K1: energies, 64 rows per block, 4 waves, high occupancy ----------
struct K1SMem {
  __hip_bfloat16 locA[64][40];    // conv feats (+pad)        5 KB
  __hip_bfloat16 locBt[128][40];  // Wloc^T [a][f] (+pad)    10 KB
  float halo[96];                 // attw halo                384 B
  float qv[DATT];
  float wsc[DATT];
};                                // ~16.5 KB

__global__ __launch_bounds__(256) void energy_kernel(
    const float* __restrict__ enc,
    const float* __restrict__ attwg,
    const __hip_bfloat16* __restrict__ WkT,
    const float* __restrict__ qvg,
    const float* __restrict__ Wloc,
    const float* __restrict__ convw,
    const float* __restrict__ convb,
    const float* __restrict__ wscore,
    float* __restrict__ energy_ws) {
  __shared__ K1SMem sm;
  const int b = blockIdx.x >> 3, rg = blockIdx.x & 7;   // 8 row-groups of 64
  const int tid = threadIdx.x;
  const int lane = tid & 63, wv = tid >> 6;             // 4 waves, 16 rows each
  const int lrow = lane & 15, lgrp = lane >> 4;

  // phase 0: fills
  if (tid < DATT) {
    sm.qv[tid]  = qvg[(size_t)b * DATT + tid];
    sm.wsc[tid] = wscore[tid];
  }
  if (tid < 96) {
    int g = rg * 64 - PW + tid;
    sm.halo[tid] = (g >= 0 && g < TT && tid < 94) ? attwg[(size_t)b * TT + g] : 0.f;
  }
  for (int i = tid; i < NF * DATT; i += 256) {
    int f = i >> 7, a = i & 127;
    sm.locBt[a][f] = __float2bfloat16(Wloc[i]);
  }
  __syncthreads();

  // conv: thread -> (row r = tid>>2, filter group fg = tid&3 -> 8 filters)
  {
    const int r = tid >> 2, fg = (tid & 3) * 8;
#pragma unroll
    for (int ff = 0; ff < 8; ++ff) {
      const int f = fg + ff;
      float a = convb[f];
      const float* cw = convw + f * KW;
#pragma unroll
      for (int k = 0; k < KW; ++k) a = fmaf(cw[k], sm.halo[r + k], a);
      sm.locA[r][f] = __float2bfloat16(a);
    }
  }
  __syncthreads();

  // loc MFMA (K=32) initializes acc
  f32x4 acc[8];
  {
    bf16x8 af = *reinterpret_cast<const bf16x8*>(&sm.locA[wv * 16 + lrow][lgrp * 8]);
#pragma unroll
    for (int n = 0; n < 8; ++n) {
      bf16x8 bl = *reinterpret_cast<const bf16x8*>(&sm.locBt[n * 16 + lrow][lgrp * 8]);
      acc[n] = __builtin_amdgcn_mfma_f32_16x16x32_bf16(
          af, bl, (f32x4){0.f, 0.f, 0.f, 0.f}, 0, 0, 0);
    }
  }

  // K-loop: depth-2 A queue, single B buffer; rely on 20+ waves/CU for latency
  const float* pa = enc + ((size_t)b * TT + rg * 64 + wv * 16 + lrow) * DENC + lgrp * 8;
  const __hip_bfloat16* pb = WkT + (size_t)lrow * 1024 + lgrp * 8;

  float4 qa0, qa1, qb0, qb1;
  bf16x8 bb[8];
  qa0 = *reinterpret_cast<const float4*>(pa);
  qa1 = *reinterpret_cast<const float4*>(pa + 4);

#define LOADB(S)                                                              \
  { _Pragma("unroll") for (int n = 0; n < 8; ++n)                             \
      bb[n] = *reinterpret_cast<const bf16x8*>(pb + (size_t)n * 16384 + (S) * 32); }
#define MFMA_STEP(Q0, Q1)                                                     \
  {                                                                           \
    union { bf16x8 v; __hip_bfloat16 h[8]; } cv_;                             \
    cv_.h[0] = __float2bfloat16(Q0.x); cv_.h[1] = __float2bfloat16(Q0.y);     \
    cv_.h[2] = __float2bfloat16(Q0.z); cv_.h[3] = __float2bfloat16(Q0.w);     \
    cv_.h[4] = __float2bfloat16(Q1.x); cv_.h[5] = __float2bfloat16(Q1.y);     \
    cv_.h[6] = __float2bfloat16(Q1.z); cv_.h[7] = __float2bfloat16(Q1.w);     \
    _Pragma("unroll") for (int n = 0; n < 8; ++n)                             \
      acc[n] = __builtin_amdgcn_mfma_f32_16x16x32_bf16(                       \
          cv_.v, bb[n], acc[n], 0, 0, 0);                                     \
  }

#pragma unroll 1
  for (int s = 0; s < 32; s += 2) {
    LOADB(s);
    qb0 = *reinterpret_cast<const float4*>(pa + (s + 1) * 32);
    qb1 = *reinterpret_cast<const float4*>(pa + (s + 1) * 32 + 4);
    MFMA_STEP(qa0, qa1);
    LOADB(s + 1);
    if (s + 2 < 32) {
      qa0 = *reinterpret_cast<const float4*>(pa + (s + 2) * 32);
      qa1 = *reinterpret_cast<const float4*>(pa + (s + 2) * 32 + 4);
    }
    MFMA_STEP(qb0, qb1);
  }
#undef LOADB
#undef MFMA_STEP

  // epilogue: e[row] = sum_a tanh(D + qv[a]) * wsc[a]
#pragma unroll
  for (int r = 0; r < 4; ++r) {
    float e = 0.f;
#pragma unroll
    for (int n = 0; n < 8; ++n) {
      const int col = n * 16 + lrow;
      float v = acc[n][r] + sm.qv[col];
      e = fmaf(fast_tanh(v), sm.wsc[col], e);
    }
    e += __shfl_xor(e, 1);
    e += __shfl_xor(e, 2);
    e += __shfl_xor(e, 4);
    e += __shfl_xor(e, 8);
    if (lrow == 0)
      energy_ws[(size_t)b * TT + rg * 64 + wv * 16 + lgrp * 4 + r] = e;
  }
}

// ---------- K2: softmax over T ----------
__global__ __launch_bounds__(512) void softmax_kernel(
    const float* __restrict__ energy_ws, float* __restrict__ out_w) {
  __shared__ float red[8];
  __shared__ float scal[2];
  const int b = blockIdx.x, tid = threadIdx.x;
  const int lane = tid & 63, wv = tid >> 6;
  const float e0 = energy_ws[(size_t)b * TT + tid];
  float m1 = e0;
#pragma unroll
  for (int off = 1; off < 64; off <<= 1) m1 = fmaxf(m1, __shfl_xor(m1, off));
  if (lane == 0) red[wv] = m1;
  __syncthreads();
  if (tid == 0) {
    float mm = red[0];
#pragma unroll
    for (int i = 1; i < 8; ++i) mm = fmaxf(mm, red[i]);
    scal[0] = mm;
  }
  __syncthreads();
  const float ex = __expf(e0 - scal[0]);
  float s1 = ex;
#pragma unroll
  for (int off = 1; off < 64; off <<= 1) s1 += __shfl_xor(s1, off);
  if (lane == 0) red[wv] = s1;
  __syncthreads();
  if (tid == 0) {
    float ss = 0.f;
#pragma unroll
    for (int i = 0; i < 8; ++i) ss += red[i];
    scal[1] = 1.f / ss;
  }
  __syncthreads();
  out_w[(size_t)b * TT + tid] = ex * scal[1];
}

// ---------- K3: context partials, 64 rows per block, pure stream ----------
__global__ __launch_bounds__(256) void ctx_partial_kernel(
    const float* __restrict__ enc, const float* __restrict__ w,
    float* __restrict__ ctxp) {
  __shared__ float ws[64];
  const int b = blockIdx.x >> 3, rg = blockIdx.x & 7;
  const int tid = threadIdx.x;
  if (tid < 64) ws[tid] = w[(size_t)b * TT + rg * 64 + tid];
  __syncthreads();
  const float* base = enc + ((size_t)b * TT + rg * 64) * DENC + tid * 4;
  float4 a = {0.f, 0.f, 0.f, 0.f};
#pragma unroll 4
  for (int r = 0; r < 64; ++r) {
    float4 v = *reinterpret_cast<const float4*>(base + (size_t)r * DENC);
    const float wt = ws[r];
    a.x = fmaf(wt, v.x, a.x);
    a.y = fmaf(wt, v.y, a.y);
    a.z = fmaf(wt, v.z, a.z);
    a.w = fmaf(wt, v.w, a.w);
  }
  *reinterpret_cast<float4*>(ctxp + ((size_t)(b * 8 + rg)) * DENC + tid * 4) = a;
}

// ---------- K4: reduce partials + context @ Wv ----------
__global__ __launch_bounds__(512) void ctx_proj_kernel(
    const float* __restrict__ ctxp, const float* __restrict__ Wv,
    float* __restrict__ out) {
  __shared__ float sc[DENC];
  const int b = blockIdx.x, tid = threadIdx.x;
  for (int i = tid; i < DENC; i += 512) {
    float s = 0.f;
#pragma unroll
    for (int qq = 0; qq < 8; ++qq) s += ctxp[((size_t)(b * 8 + qq)) * DENC + i];
    sc[i] = s;
  }
  __syncthreads();
  float acc = 0.f;
#pragma unroll 8
  for (int dd = 0; dd < DENC; ++dd)
    acc = fmaf(sc[dd], Wv[(size_t)dd * DDEC + tid], acc);
  out[(size_t)b * DDEC + tid] = acc;
}

extern "C" void kernel_launch(void* const* d_in, const int* in_sizes, int n_in,
                              void* d_out, int out_size, void* d_ws, size_t ws_size,
                              hipStream_t stream) {
  const float* query  = (const float*)d_in[0];
  const float* enc    = (const float*)d_in[1];
  const float* attw   = (const float*)d_in[2];
  const float* Wq     = (const float*)d_in[3];
  const float* Wk     = (const float*)d_in[4];
  const float* Wv     = (const float*)d_in[5];
  const float* Wloc   = (const float*)d_in[6];
  const float* convw  = (const float*)d_in[7];
  const float* convb  = (const float*)d_in[8];
  const float* wscore = (const float*)d_in[9];

  float* ctx  = (float*)d_out;               // [256][512]
  float* neww = (float*)d_out + NB * TT;     // [256][512]

  char* ws = (char*)d_ws;
  float* ctxp      = (float*)ws;                               // 2048*1024*4 = 8MB
  __hip_bfloat16* WkT = (__hip_bfloat16*)(ws + 8388608);       // 256KB
  float* qvg       = (float*)(ws + 8388608 + 262144);          // 128KB
  float* energy_ws = (float*)(ws + 8388608 + 262144 + 131072); // 512KB

  hipLaunchKernelGGL(prep_wkt, dim3(256), dim3(256), 0, stream, Wk, WkT);
  hipLaunchKernelGGL(prep_qv, dim3(NB), dim3(128), 0, stream, query, Wq, qvg);
  hipLaunchKernelGGL(energy_kernel, dim3(NB * 8), dim3(256), 0, stream,
                     enc, attw, WkT, qvg, Wloc, convw, convb, wscore, energy_ws);
  hipLaunchKernelGGL(softmax_kernel, dim3(NB), dim3(512), 0, stream,
                     energy_ws, neww);
  hipLaunchKernelGGL(ctx_partial_kernel, dim3(NB * 8), dim3(256), 0, stream,
                     enc, neww, ctxp);
  hipLaunchKernelGGL(ctx_proj_kernel, dim3(NB), dim3(512), 0, stream,
                     ctxp, Wv, ctx);
}

// Round 8
// 511.116 us; speedup vs baseline: 1.0122x; 1.0122x over previous
//
#include <hip/hip_runtime.h>
#include <hip/hip_bf16.h>

typedef __attribute__((ext_vector_type(8))) short bf16x8;
typedef __attribute__((ext_vector_type(4))) float f32x4;

#define NB   256
#define TT   512
#define DDEC 512
#define DENC 1024
#define DATT 128
#define NF   32
#define KW   31
#define PW   15

// global -> LDS direct DMA, 16B/lane; dest = wave-uniform base + lane*16.
#define GLDS16(g, l)                                                        \
  __builtin_amdgcn_global_load_lds(                                         \
      (const __attribute__((address_space(1))) void*)(uintptr_t)(g),        \
      (__attribute__((address_space(3))) void*)(uintptr_t)(l), 16, 0, 0)

__device__ __forceinline__ float fast_tanh(float x) {
  float e = __expf(2.f * x);
  return 1.f - 2.f / (e + 1.f);
}

// ---------- prep: WkT[a][k] = bf16(Wk[k][a]) ----------
__global__ __launch_bounds__(256) void prep_wkt(const float* __restrict__ Wk,
                                                __hip_bfloat16* __restrict__ WkT) {
  int idx = blockIdx.x * 256 + threadIdx.x;
  int k2 = idx >> 7, a = idx & 127;
  int k = k2 * 2;
  union { ushort2 u; __hip_bfloat16 h[2]; } cv;
  cv.h[0] = __float2bfloat16(Wk[(size_t)k * DATT + a]);
  cv.h[1] = __float2bfloat16(Wk[(size_t)(k + 1) * DATT + a]);
  *reinterpret_cast<ushort2*>(WkT + (size_t)a * 1024 + k) = cv.u;
}

// ---------- prep: qv[b][a] = query[b,:] @ Wq[:,a] ----------
__global__ __launch_bounds__(128) void prep_qv(const float* __restrict__ query,
                                               const float* __restrict__ Wq,
                                               float* __restrict__ qvg) {
  __shared__ float qr[DDEC];
  const int b = blockIdx.x, tid = threadIdx.x;
  for (int i = tid; i < DDEC; i += 128) qr[i] = query[(size_t)b * DDEC + i];
  __syncthreads();
  float a0 = 0.f, a1 = 0.f, a2 = 0.f, a3 = 0.f;
#pragma unroll 4
  for (int d = 0; d < DDEC; d += 4) {
    a0 = fmaf(qr[d + 0], Wq[(size_t)(d + 0) * DATT + tid], a0);
    a1 = fmaf(qr[d + 1], Wq[(size_t)(d + 1) * DATT + tid], a1);
    a2 = fmaf(qr[d + 2], Wq[(size_t)(d + 2) * DATT + tid], a2);
    a3 = fmaf(qr[d + 3], Wq[(size_t)(d + 3) * DATT + tid], a3);
  }
  qvg[(size_t)b * DATT + tid] = (a0 + a1) + (a2 + a3);
}

// ---------- K1: energies. 16 rows/block, 4 waves = 4 K-slices. ----------
// A staged to LDS in FULL 1KB contiguous row-segments (one GLDS16 = one row).
struct K1SMem {
  float au[2][16][256];            // 32KB: A tile dbuf; reused as red[4][16][128]
  __hip_bfloat16 locA[16][40];     // conv feats
  __hip_bfloat16 locBt[128][40];   // Wloc^T [a][f]
  float halo[48];
  float qv[DATT];
  float wsc[DATT];
};                                 // ~45KB -> 3 blocks/CU (LDS-wise)

__global__ __launch_bounds__(256) void energy_kernel(
    const float* __restrict__ enc,
    const float* __restrict__ attwg,
    const __hip_bfloat16* __restrict__ WkT,
    const float* __restrict__ qvg,
    const float* __restrict__ Wloc,
    const float* __restrict__ convw,
    const float* __restrict__ convb,
    const float* __restrict__ wscore,
    float* __restrict__ energy_ws) {
  __shared__ K1SMem sm;
  const int b = blockIdx.x >> 5, rg = blockIdx.x & 31;  // 32 rowgroups of 16
  const int tid = threadIdx.x;
  const int lane = tid & 63, ks = tid >> 6;             // wave = K-slice 0..3
  const int lrow = lane & 15, lgrp = lane >> 4;
  const size_t rowbase = (size_t)b * TT + rg * 16;

  // ---- stage chunk 0 immediately: 1 GLDS16 per row, 1KB contiguous ----
  // LDS slot s of row r holds global 16B-chunk (s ^ (r&7))  [T2 pre-swizzled src]
#pragma unroll
  for (int i = 0; i < 4; ++i) {
    const int r = ks * 4 + i;
    const float* src = enc + (rowbase + r) * DENC + ((lane ^ (r & 7)) << 2);
    GLDS16(src, &sm.au[0][r][0]);
  }

  // ---- small fills ----
  if (tid < DATT) sm.qv[tid] = qvg[(size_t)b * DATT + tid];
  else if (tid < 2 * DATT) sm.wsc[tid - DATT] = wscore[tid - DATT];
  if (tid < 48) {
    int g = rg * 16 - PW + tid;
    sm.halo[tid] = (g >= 0 && g < TT && tid < 46) ? attwg[(size_t)b * TT + g] : 0.f;
  }
  for (int i = tid; i < NF * DATT; i += 256)
    sm.locBt[i & 127][i >> 7] = __float2bfloat16(Wloc[i]);
  __syncthreads();

  // ---- conv: thread (row=tid>>4, 2 filters) ----
  {
    const int r = tid >> 4, f2 = (tid & 15) * 2;
#pragma unroll
    for (int ff = 0; ff < 2; ++ff) {
      const int f = f2 + ff;
      float a = convb[f];
      const float* cw = convw + f * KW;
#pragma unroll
      for (int k = 0; k < KW; ++k) a = fmaf(cw[k], sm.halo[r + k], a);
      sm.locA[r][f] = __float2bfloat16(a);
    }
  }
  __syncthreads();

  // ---- loc MFMA (K=32) on wave ks==0 initializes its partial; others zero ----
  f32x4 acc[8];
  if (ks == 0) {
    bf16x8 af = *reinterpret_cast<const bf16x8*>(&sm.locA[lrow][lgrp * 8]);
#pragma unroll
    for (int n = 0; n < 8; ++n) {
      bf16x8 bl = *reinterpret_cast<const bf16x8*>(&sm.locBt[n * 16 + lrow][lgrp * 8]);
      acc[n] = __builtin_amdgcn_mfma_f32_16x16x32_bf16(
          af, bl, (f32x4){0.f, 0.f, 0.f, 0.f}, 0, 0, 0);
    }
  } else {
#pragma unroll
    for (int n = 0; n < 8; ++n) acc[n] = (f32x4){0.f, 0.f, 0.f, 0.f};
  }

  // ---- K-chunk loop: 4 chunks x 256K. Wave ks owns K-window ks*64..+64 ----
  bf16x8 bb[2][8];
#pragma unroll 1
  for (int c = 0; c < 4; ++c) {
    const int cur = c & 1;
    // B for both ksteps of this chunk (L2-hot WkT)
#pragma unroll
    for (int st = 0; st < 2; ++st)
#pragma unroll
      for (int n = 0; n < 8; ++n)
        bb[st][n] = *reinterpret_cast<const bf16x8*>(
            WkT + (size_t)(n * 16 + lrow) * 1024 + c * 256 + ks * 64 + st * 32 + lgrp * 8);
    __builtin_amdgcn_sched_barrier(0);
    asm volatile("s_waitcnt vmcnt(0)" ::: "memory");   // stage(c)+B retired
    __builtin_amdgcn_sched_barrier(0);
    __builtin_amdgcn_s_barrier();                       // tile c visible block-wide
    __builtin_amdgcn_sched_barrier(0);
    if (c < 3) {                                        // prefetch chunk c+1
#pragma unroll
      for (int i = 0; i < 4; ++i) {
        const int r = ks * 4 + i;
        const float* src =
            enc + (rowbase + r) * DENC + (c + 1) * 256 + ((lane ^ (r & 7)) << 2);
        GLDS16(src, &sm.au[cur ^ 1][r][0]);
      }
    }
    const char* base = (const char*)&sm.au[cur][0][0];
    const int x = lrow & 7;
#pragma unroll
    for (int st = 0; st < 2; ++st) {
      const int g = ks * 16 + st * 8 + lgrp * 2;
      float4 f0 = *reinterpret_cast<const float4*>(base + lrow * 1024 + ((g ^ x) << 4));
      float4 f1 = *reinterpret_cast<const float4*>(base + lrow * 1024 + (((g + 1) ^ x) << 4));
      union { bf16x8 v; __hip_bfloat16 h[8]; } cv;
      cv.h[0] = __float2bfloat16(f0.x); cv.h[1] = __float2bfloat16(f0.y);
      cv.h[2] = __float2bfloat16(f0.z); cv.h[3] = __float2bfloat16(f0.w);
      cv.h[4] = __float2bfloat16(f1.x); cv.h[5] = __float2bfloat16(f1.y);
      cv.h[6] = __float2bfloat16(f1.z); cv.h[7] = __float2bfloat16(f1.w);
#pragma unroll
      for (int n = 0; n < 8; ++n)
        acc[n] = __builtin_amdgcn_mfma_f32_16x16x32_bf16(cv.v, bb[st][n], acc[n], 0, 0, 0);
    }
  }

  // ---- reduce K-slice partials via LDS (reuse au as red[4][16][128]) ----
  __syncthreads();
  float* red = &sm.au[0][0][0];
#pragma unroll
  for (int n = 0; n < 8; ++n)
#pragma unroll
    for (int r = 0; r < 4; ++r)
      red[ks * 2048 + (lgrp * 4 + r) * 128 + n * 16 + lrow] = acc[n][r];
  __syncthreads();

  // ---- combine + tanh*wscore + 16-lane reduce ----
  {
    const int row = tid >> 4, cg = tid & 15;
    float e = 0.f;
#pragma unroll
    for (int half = 0; half < 2; ++half) {
      f32x4 s = (f32x4){0.f, 0.f, 0.f, 0.f};
#pragma unroll
      for (int k4 = 0; k4 < 4; ++k4)
        s += *reinterpret_cast<const f32x4*>(&red[k4 * 2048 + row * 128 + cg * 8 + half * 4]);
#pragma unroll
      for (int j = 0; j < 4; ++j) {
        const int col = cg * 8 + half * 4 + j;
        float v = s[j] + sm.qv[col];
        e = fmaf(fast_tanh(v), sm.wsc[col], e);
      }
    }
    e += __shfl_xor(e, 1);
    e += __shfl_xor(e, 2);
    e += __shfl_xor(e, 4);
    e += __shfl_xor(e, 8);
    if (cg == 0) energy_ws[(size_t)b * TT + rg * 16 + row] = e;
  }
}

// ---------- K2: softmax over T ----------
__global__ __launch_bounds__(512) void softmax_kernel(
    const float* __restrict__ energy_ws, float* __restrict__ out_w) {
  __shared__ float red[8];
  __shared__ float scal[2];
  const int b = blockIdx.x, tid = threadIdx.x;
  const int lane = tid & 63, wv = tid >> 6;
  const float e0 = energy_ws[(size_t)b * TT + tid];
  float m1 = e0;
#pragma unroll
  for (int off = 1; off < 64; off <<= 1) m1 = fmaxf(m1, __shfl_xor(m1, off));
  if (lane == 0) red[wv] = m1;
  __syncthreads();
  if (tid == 0) {
    float mm = red[0];
#pragma unroll
    for (int i = 1; i < 8; ++i) mm = fmaxf(mm, red[i]);
    scal[0] = mm;
  }
  __syncthreads();
  const float ex = __expf(e0 - scal[0]);
  float s1 = ex;
#pragma unroll
  for (int off = 1; off < 64; off <<= 1) s1 += __shfl_xor(s1, off);
  if (lane == 0) red[wv] = s1;
  __syncthreads();
  if (tid == 0) {
    float ss = 0.f;
#pragma unroll
    for (int i = 0; i < 8; ++i) ss += red[i];
    scal[1] = 1.f / ss;
  }
  __syncthreads();
  out_w[(size_t)b * TT + tid] = ex * scal[1];
}

// ---------- K3: context partials, 1KB-contiguous reads ----------
__global__ __launch_bounds__(256) void ctx_partial_kernel(
    const float* __restrict__ enc, const float* __restrict__ w,
    float* __restrict__ ctxp) {
  __shared__ float ws[64];
  const int b = blockIdx.x >> 3, rg = blockIdx.x & 7;
  const int tid = threadIdx.x;
  if (tid < 64) ws[tid] = w[(size_t)b * TT + rg * 64 + tid];
  __syncthreads();
  const float* base = enc + ((size_t)b * TT + rg * 64) * DENC + tid * 4;
  float4 a = {0.f, 0.f, 0.f, 0.f};
#pragma unroll 8
  for (int r = 0; r < 64; ++r) {
    float4 v = *reinterpret_cast<const float4*>(base + (size_t)r * DENC);
    const float wt = ws[r];
    a.x = fmaf(wt, v.x, a.x);
    a.y = fmaf(wt, v.y, a.y);
    a.z = fmaf(wt, v.z, a.z);
    a.w = fmaf(wt, v.w, a.w);
  }
  *reinterpret_cast<float4*>(ctxp + ((size_t)(b * 8 + rg)) * DENC + tid * 4) = a;
}

// ---------- K4: reduce partials + context @ Wv ----------
__global__ __launch_bounds__(512) void ctx_proj_kernel(
    const float* __restrict__ ctxp, const float* __restrict__ Wv,
    float* __restrict__ out) {
  __shared__ float sc[DENC];
  const int b = blockIdx.x, tid = threadIdx.x;
  for (int i = tid; i < DENC; i += 512) {
    float s = 0.f;
#pragma unroll
    for (int qq = 0; qq < 8; ++qq) s += ctxp[((size_t)(b * 8 + qq)) * DENC + i];
    sc[i] = s;
  }
  __syncthreads();
  float acc = 0.f;
#pragma unroll 8
  for (int dd = 0; dd < DENC; ++dd)
    acc = fmaf(sc[dd], Wv[(size_t)dd * DDEC + tid], acc);
  out[(size_t)b * DDEC + tid] = acc;
}

extern "C" void kernel_launch(void* const* d_in, const int* in_sizes, int n_in,
                              void* d_out, int out_size, void* d_ws, size_t ws_size,
                              hipStream_t stream) {
  const float* query  = (const float*)d_in[0];
  const float* enc    = (const float*)d_in[1];
  const float* attw   = (const float*)d_in[2];
  const float* Wq     = (const float*)d_in[3];
  const float* Wk     = (const float*)d_in[4];
  const float* Wv     = (const float*)d_in[5];
  const float* Wloc   = (const float*)d_in[6];
  const float* convw  = (const float*)d_in[7];
  const float* convb  = (const float*)d_in[8];
  const float* wscore = (const float*)d_in[9];

  float* ctx  = (float*)d_out;               // [256][512]
  float* neww = (float*)d_out + NB * TT;     // [256][512]

  char* ws = (char*)d_ws;
  float* ctxp      = (float*)ws;                               // 8MB
  __hip_bfloat16* WkT = (__hip_bfloat16*)(ws + 8388608);       // 256KB
  float* qvg       = (float*)(ws + 8388608 + 262144);          // 128KB
  float* energy_ws = (float*)(ws + 8388608 + 262144 + 131072); // 512KB

  hipLaunchKernelGGL(prep_wkt, dim3(256), dim3(256), 0, stream, Wk, WkT);
  hipLaunchKernelGGL(prep_qv, dim3(NB), dim3(128), 0, stream, query, Wq, qvg);
  hipLaunchKernelGGL(energy_kernel, dim3(NB * 32), dim3(256), 0, stream,
                     enc, attw, WkT, qvg, Wloc, convw, convb, wscore, energy_ws);
  hipLaunchKernelGGL(softmax_kernel, dim3(NB), dim3(512), 0, stream,
                     energy_ws, neww);
  hipLaunchKernelGGL(ctx_partial_kernel, dim3(NB * 8), dim3(256), 0, stream,
                     enc, neww, ctxp);
  hipLaunchKernelGGL(ctx_proj_kernel, dim3(NB), dim3(512), 0, stream,
                     ctxp, Wv, ctx);
}

// Round 10
// 451.662 us; speedup vs baseline: 1.1455x; 1.1316x over previous
//
#include <hip/hip_runtime.h>
#include <hip/hip_bf16.h>

typedef __attribute__((ext_vector_type(8))) short bf16x8;
typedef __attribute__((ext_vector_type(4))) float f32x4;

#define NB   256
#define TT   512
#define DDEC 512
#define DENC 1024
#define DATT 128
#define NF   32
#define KW   31
#define PW   15

__device__ __forceinline__ float fast_tanh(float x) {
  float e = __expf(2.f * x);
  return 1.f - 2.f / (e + 1.f);
}

// ---------- prep: WkT[a][k] = bf16(Wk[k][a]) ----------
__global__ __launch_bounds__(256) void prep_wkt(const float* __restrict__ Wk,
                                                __hip_bfloat16* __restrict__ WkT) {
  int idx = blockIdx.x * 256 + threadIdx.x;
  int k2 = idx >> 7, a = idx & 127;
  int k = k2 * 2;
  union { ushort2 u; __hip_bfloat16 h[2]; } cv;
  cv.h[0] = __float2bfloat16(Wk[(size_t)k * DATT + a]);
  cv.h[1] = __float2bfloat16(Wk[(size_t)(k + 1) * DATT + a]);
  *reinterpret_cast<ushort2*>(WkT + (size_t)a * 1024 + k) = cv.u;
}

// ---------- prep: wlocT[a][f] = bf16(Wloc[f][a]) ----------
__global__ __launch_bounds__(256) void prep_wloc(const float* __restrict__ Wloc,
                                                 __hip_bfloat16* __restrict__ wlocT) {
  int idx = blockIdx.x * 256 + threadIdx.x;   // 4096 = (a,f)
  int a = idx >> 5, f = idx & 31;
  wlocT[idx] = __float2bfloat16(Wloc[(size_t)f * DATT + a]);
}

// ---------- prep: qv[b][a] = query[b,:] @ Wq[:,a] ----------
__global__ __launch_bounds__(128) void prep_qv(const float* __restrict__ query,
                                               const float* __restrict__ Wq,
                                               float* __restrict__ qvg) {
  __shared__ float qr[DDEC];
  const int b = blockIdx.x, tid = threadIdx.x;
  for (int i = tid; i < DDEC; i += 128) qr[i] = query[(size_t)b * DDEC + i];
  __syncthreads();
  float a0 = 0.f, a1 = 0.f, a2 = 0.f, a3 = 0.f;
#pragma unroll 4
  for (int d = 0; d < DDEC; d += 4) {
    a0 = fmaf(qr[d + 0], Wq[(size_t)(d + 0) * DATT + tid], a0);
    a1 = fmaf(qr[d + 1], Wq[(size_t)(d + 1) * DATT + tid], a1);
    a2 = fmaf(qr[d + 2], Wq[(size_t)(d + 2) * DATT + tid], a2);
    a3 = fmaf(qr[d + 3], Wq[(size_t)(d + 3) * DATT + tid], a3);
  }
  qvg[(size_t)b * DATT + tid] = (a0 + a1) + (a2 + a3);
}

// ---------- prep: locf[b][t][f] = bf16(conv1d(attw)[f][t]) ----------
__global__ __launch_bounds__(512) void prep_locf(const float* __restrict__ attwg,
                                                 const float* __restrict__ convw,
                                                 const float* __restrict__ convb,
                                                 __hip_bfloat16* __restrict__ locf) {
  __shared__ float at[TT + 2 * PW];
  __shared__ float cw[NF][KW];
  __shared__ float cb[NF];
  const int b = blockIdx.x, t = threadIdx.x;
  for (int i = t; i < TT + 2 * PW; i += 512) {
    int g = i - PW;
    at[i] = (g >= 0 && g < TT) ? attwg[(size_t)b * TT + g] : 0.f;
  }
  for (int i = t; i < NF * KW; i += 512) cw[i / KW][i % KW] = convw[i];
  if (t < NF) cb[t] = convb[t];
  __syncthreads();
  union { __hip_bfloat16 h[NF]; ushort4 u4[8]; } o;
#pragma unroll
  for (int f = 0; f < NF; ++f) {
    float a = cb[f];
#pragma unroll
    for (int k = 0; k < KW; ++k) a = fmaf(cw[f][k], at[t + k], a);
    o.h[f] = __float2bfloat16(a);
  }
  ushort4* dst = reinterpret_cast<ushort4*>(locf + ((size_t)b * TT + t) * NF);
#pragma unroll
  for (int i = 0; i < 8; ++i) dst[i] = o.u4[i];
}

// ---------- energy: loop-inverted, barrier-free, depth-2 dual reg queues ----
struct EVSmem {
  float qv[DATT];
  float wsc[DATT];
  float epart[64];
};

__global__ __launch_bounds__(256, 3) void energy_v2(
    const float* __restrict__ enc,
    const __hip_bfloat16* __restrict__ WkT,
    const __hip_bfloat16* __restrict__ wlocT,
    const __hip_bfloat16* __restrict__ locf,
    const float* __restrict__ qvg,
    const float* __restrict__ wscore,
    float* __restrict__ energy_ws) {
  __shared__ EVSmem sm;
  const int b = blockIdx.x >> 3, rc = blockIdx.x & 7;   // 8 chunks of 64 rows
  const int tid = threadIdx.x, lane = tid & 63, wv = tid >> 6;
  const int rg = wv >> 1, ch = wv & 1;                  // rowgroup(32) x colhalf(64)
  const int lrow = lane & 15, lgrp = lane >> 4;
  const int R0 = rc * 64;

  if (tid < DATT) sm.qv[tid] = qvg[(size_t)b * DATT + tid];
  else sm.wsc[tid - DATT] = wscore[tid - DATT];
  __syncthreads();

  const float* pa =
      enc + ((size_t)b * TT + R0 + rg * 32 + lrow) * DENC + lgrp * 8;
  const __hip_bfloat16* pb = WkT + (size_t)(ch * 64 + lrow) * 1024 + lgrp * 8;

  float4 aq0[4], aq1[4];
  bf16x8 bb0[4], bb1[4];
  f32x4 acc[2][4];
#pragma unroll
  for (int m = 0; m < 2; ++m)
#pragma unroll
    for (int n = 0; n < 4; ++n) acc[m][n] = (f32x4){0.f, 0.f, 0.f, 0.f};

#define ELOADA(Q, S)                                                          \
  {                                                                           \
    _Pragma("unroll") for (int m = 0; m < 2; ++m) {                           \
      const float* p_ = pa + (size_t)m * 16 * DENC + (S) * 32;                \
      Q[2 * m]     = *reinterpret_cast<const float4*>(p_);                    \
      Q[2 * m + 1] = *reinterpret_cast<const float4*>(p_ + 4);                \
    }                                                                         \
  }
#define ELOADB(BB, S)                                                         \
  {                                                                           \
    _Pragma("unroll") for (int n = 0; n < 4; ++n)                             \
      BB[n] = *reinterpret_cast<const bf16x8*>(                               \
          pb + (size_t)n * 16 * 1024 + (S) * 32);                             \
  }
#define ESTEP(Q, BB)                                                          \
  {                                                                           \
    _Pragma("unroll") for (int m = 0; m < 2; ++m) {                           \
      union { bf16x8 v; __hip_bfloat16 h[8]; } cv_;                           \
      cv_.h[0] = __float2bfloat16(Q[2 * m].x);                                \
      cv_.h[1] = __float2bfloat16(Q[2 * m].y);                                \
      cv_.h[2] = __float2bfloat16(Q[2 * m].z);                                \
      cv_.h[3] = __float2bfloat16(Q[2 * m].w);                                \
      cv_.h[4] = __float2bfloat16(Q[2 * m + 1].x);                            \
      cv_.h[5] = __float2bfloat16(Q[2 * m + 1].y);                            \
      cv_.h[6] = __float2bfloat16(Q[2 * m + 1].z);                            \
      cv_.h[7] = __float2bfloat16(Q[2 * m + 1].w);                            \
      _Pragma("unroll") for (int n = 0; n < 4; ++n)                           \
        acc[m][n] = __builtin_amdgcn_mfma_f32_16x16x32_bf16(                  \
            cv_.v, BB[n], acc[m][n], 0, 0, 0);                                \
    }                                                                         \
  }

  // FULL K: DENC=1024 -> 32 steps of K=32 (R9 bug: only 16 steps)
  ELOADA(aq0, 0); ELOADB(bb0, 0);
  ELOADA(aq1, 1); ELOADB(bb1, 1);
#pragma unroll 1
  for (int s = 0; s < 28; s += 2) {
    ESTEP(aq0, bb0);
    ELOADA(aq0, s + 2); ELOADB(bb0, s + 2);
    ESTEP(aq1, bb1);
    ELOADA(aq1, s + 3); ELOADB(bb1, s + 3);
  }
  ESTEP(aq0, bb0);                     // s=28
  ELOADA(aq0, 30); ELOADB(bb0, 30);
  ESTEP(aq1, bb1);                     // s=29
  ELOADA(aq1, 31); ELOADB(bb1, 31);
  ESTEP(aq0, bb0);                     // s=30
  // loc-step loads (K=32 of location features)
  bf16x8 alA[2], blB[4];
  {
    const __hip_bfloat16* pl =
        locf + ((size_t)b * TT + R0 + rg * 32 + lrow) * NF + lgrp * 8;
#pragma unroll
    for (int m = 0; m < 2; ++m)
      alA[m] = *reinterpret_cast<const bf16x8*>(pl + (size_t)m * 16 * NF);
    const __hip_bfloat16* pw = wlocT + (size_t)(ch * 64 + lrow) * NF + lgrp * 8;
#pragma unroll
    for (int n = 0; n < 4; ++n)
      blB[n] = *reinterpret_cast<const bf16x8*>(pw + (size_t)n * 16 * NF);
  }
  ESTEP(aq1, bb1);                     // s=31 (hides loc-load latency)
#pragma unroll
  for (int m = 0; m < 2; ++m)
#pragma unroll
    for (int n = 0; n < 4; ++n)
      acc[m][n] = __builtin_amdgcn_mfma_f32_16x16x32_bf16(
          alA[m], blB[n], acc[m][n], 0, 0, 0);
#undef ELOADA
#undef ELOADB
#undef ESTEP

  // epilogue: per-colhalf partial e[row]; combine across ch via LDS
  float evals[2][4];
#pragma unroll
  for (int m = 0; m < 2; ++m) {
#pragma unroll
    for (int r = 0; r < 4; ++r) {
      float e = 0.f;
#pragma unroll
      for (int n = 0; n < 4; ++n) {
        const int col = ch * 64 + n * 16 + lrow;
        float v = acc[m][n][r] + sm.qv[col];
        e = fmaf(fast_tanh(v), sm.wsc[col], e);
      }
      e += __shfl_xor(e, 1);
      e += __shfl_xor(e, 2);
      e += __shfl_xor(e, 4);
      e += __shfl_xor(e, 8);
      evals[m][r] = e;
      if (ch == 0 && lrow == 0) sm.epart[rg * 32 + m * 16 + lgrp * 4 + r] = e;
    }
  }
  __syncthreads();
  if (ch == 1 && lrow == 0) {
#pragma unroll
    for (int m = 0; m < 2; ++m)
#pragma unroll
      for (int r = 0; r < 4; ++r) {
        const int row = rg * 32 + m * 16 + lgrp * 4 + r;
        energy_ws[(size_t)b * TT + R0 + row] = evals[m][r] + sm.epart[row];
      }
  }
}

// ---------- softmax over T ----------
__global__ __launch_bounds__(512) void softmax_kernel(
    const float* __restrict__ energy_ws, float* __restrict__ out_w) {
  __shared__ float red[8];
  __shared__ float scal[2];
  const int b = blockIdx.x, tid = threadIdx.x;
  const int lane = tid & 63, wv = tid >> 6;
  const float e0 = energy_ws[(size_t)b * TT + tid];
  float m1 = e0;
#pragma unroll
  for (int off = 1; off < 64; off <<= 1) m1 = fmaxf(m1, __shfl_xor(m1, off));
  if (lane == 0) red[wv] = m1;
  __syncthreads();
  if (tid == 0) {
    float mm = red[0];
#pragma unroll
    for (int i = 1; i < 8; ++i) mm = fmaxf(mm, red[i]);
    scal[0] = mm;
  }
  __syncthreads();
  const float ex = __expf(e0 - scal[0]);
  float s1 = ex;
#pragma unroll
  for (int off = 1; off < 64; off <<= 1) s1 += __shfl_xor(s1, off);
  if (lane == 0) red[wv] = s1;
  __syncthreads();
  if (tid == 0) {
    float ss = 0.f;
#pragma unroll
    for (int i = 0; i < 8; ++i) ss += red[i];
    scal[1] = 1.f / ss;
  }
  __syncthreads();
  out_w[(size_t)b * TT + tid] = ex * scal[1];
}

// ---------- ctx partials: 128 rows/block, contiguous float4 stream ----------
__global__ __launch_bounds__(256) void ctx_partial_kernel(
    const float* __restrict__ enc, const float* __restrict__ w,
    float* __restrict__ ctxp) {
  __shared__ float ws[128];
  const int b = blockIdx.x >> 2, q = blockIdx.x & 3;
  const int tid = threadIdx.x;
  if (tid < 128) ws[tid] = w[(size_t)b * TT + q * 128 + tid];
  __syncthreads();
  const float* base = enc + ((size_t)b * TT + q * 128) * DENC + tid * 4;
  float4 a = {0.f, 0.f, 0.f, 0.f};
#pragma unroll 8
  for (int r = 0; r < 128; ++r) {
    float4 v = *reinterpret_cast<const float4*>(base + (size_t)r * DENC);
    const float wt = ws[r];
    a.x = fmaf(wt, v.x, a.x);
    a.y = fmaf(wt, v.y, a.y);
    a.z = fmaf(wt, v.z, a.z);
    a.w = fmaf(wt, v.w, a.w);
  }
  *reinterpret_cast<float4*>(ctxp + ((size_t)(b * 4 + q)) * DENC + tid * 4) = a;
}

// ---------- reduce partials + context @ Wv ----------
__global__ __launch_bounds__(512) void ctx_proj_kernel(
    const float* __restrict__ ctxp, const float* __restrict__ Wv,
    float* __restrict__ out) {
  __shared__ float sc[DENC];
  const int b = blockIdx.x, tid = threadIdx.x;
  for (int i = tid; i < DENC; i += 512) {
    float s = 0.f;
#pragma unroll
    for (int qq = 0; qq < 4; ++qq) s += ctxp[((size_t)(b * 4 + qq)) * DENC + i];
    sc[i] = s;
  }
  __syncthreads();
  float acc = 0.f;
#pragma unroll 8
  for (int dd = 0; dd < DENC; ++dd)
    acc = fmaf(sc[dd], Wv[(size_t)dd * DDEC + tid], acc);
  out[(size_t)b * DDEC + tid] = acc;
}

extern "C" void kernel_launch(void* const* d_in, const int* in_sizes, int n_in,
                              void* d_out, int out_size, void* d_ws, size_t ws_size,
                              hipStream_t stream) {
  const float* query  = (const float*)d_in[0];
  const float* enc    = (const float*)d_in[1];
  const float* attw   = (const float*)d_in[2];
  const float* Wq     = (const float*)d_in[3];
  const float* Wk     = (const float*)d_in[4];
  const float* Wv     = (const float*)d_in[5];
  const float* Wloc   = (const float*)d_in[6];
  const float* convw  = (const float*)d_in[7];
  const float* convb  = (const float*)d_in[8];
  const float* wscore = (const float*)d_in[9];

  float* ctx  = (float*)d_out;               // [256][512]
  float* neww = (float*)d_out + NB * TT;     // [256][512]

  char* ws = (char*)d_ws;
  float* ctxp            = (float*)ws;                       // 4 MB
  __hip_bfloat16* WkT    = (__hip_bfloat16*)(ws + 4194304);  // 256 KB
  float* qvg             = (float*)(ws + 4456448);           // 128 KB
  float* energy_ws       = (float*)(ws + 4587520);           // 512 KB
  __hip_bfloat16* wlocT  = (__hip_bfloat16*)(ws + 5111808);  // 8 KB
  __hip_bfloat16* locf   = (__hip_bfloat16*)(ws + 5120000);  // 8 MB

  hipLaunchKernelGGL(prep_wkt, dim3(256), dim3(256), 0, stream, Wk, WkT);
  hipLaunchKernelGGL(prep_wloc, dim3(16), dim3(256), 0, stream, Wloc, wlocT);
  hipLaunchKernelGGL(prep_qv, dim3(NB), dim3(128), 0, stream, query, Wq, qvg);
  hipLaunchKernelGGL(prep_locf, dim3(NB), dim3(512), 0, stream,
                     attw, convw, convb, locf);
  hipLaunchKernelGGL(energy_v2, dim3(NB * 8), dim3(256), 0, stream,
                     enc, WkT, wlocT, locf, qvg, wscore, energy_ws);
  hipLaunchKernelGGL(softmax_kernel, dim3(NB), dim3(512), 0, stream,
                     energy_ws, neww);
  hipLaunchKernelGGL(ctx_partial_kernel, dim3(NB * 4), dim3(256), 0, stream,
                     enc, neww, ctxp);
  hipLaunchKernelGGL(ctx_proj_kernel, dim3(NB), dim3(512), 0, stream,
                     ctxp, Wv, ctx);
}